// Round 1
// baseline (279.425 us; speedup 1.0000x reference)
//
#include <hip/hip_runtime.h>
#include <cstdint>
#include <cstddef>

#define B_    32
#define S_    2048
#define D_    64
#define QBLK  32            // q rows per block
#define SP    2056          // padded P_lds row stride (shorts): 2048 + 8

typedef __attribute__((ext_vector_type(8))) short short8_t;  // 8 bf16 (4 VGPRs)
typedef __attribute__((ext_vector_type(4))) float f32x4;     // MFMA acc

__device__ __forceinline__ short f2bf(float f) {
  union { float f; unsigned u; } x; x.f = f;
  unsigned u = x.u;
  u += 0x7fffu + ((u >> 16) & 1u);   // round-to-nearest-even
  return (short)(u >> 16);
}
__device__ __forceinline__ float bf2f(short s) {
  union { unsigned u; float f; } x;
  x.u = ((unsigned)(unsigned short)s) << 16;
  return x.f;
}

// ---- fp32 -> bf16 elementwise (for K) ----
__global__ void convert_bf16_kernel(const float* __restrict__ in,
                                    short* __restrict__ out, int n4) {
  int i = blockIdx.x * blockDim.x + threadIdx.x;
  if (i >= n4) return;
  f32x4 f = ((const f32x4*)in)[i];
  short4 o;
  o.x = f2bf(f[0]); o.y = f2bf(f[1]); o.z = f2bf(f[2]); o.w = f2bf(f[3]);
  ((short4*)out)[i] = o;
}

// ---- V [B][S][D] fp32 -> Vt [B][D][S] bf16 (so PV B-frags are contiguous) ----
__global__ void transpose_v_kernel(const float* __restrict__ v,
                                   short* __restrict__ vt) {
  __shared__ float t[64][65];                 // +1 pad: conflict-free col reads
  int b   = blockIdx.x >> 5;                  // S_/64 = 32 tiles per batch
  int st  = blockIdx.x & 31;
  int tid = threadIdx.x;
  const float* src = v + ((size_t)(b * S_ + st * 64)) * D_;
#pragma unroll
  for (int p = 0; p < 4; ++p) {
    int r = p * 16 + (tid >> 4);
    int c = (tid & 15) * 4;
    f32x4 f = *(const f32x4*)(src + (size_t)r * D_ + c);
    t[r][c] = f[0]; t[r][c+1] = f[1]; t[r][c+2] = f[2]; t[r][c+3] = f[3];
  }
  __syncthreads();
#pragma unroll
  for (int p = 0; p < 8; ++p) {
    int d  = p * 8 + (tid >> 5);
    int si = (tid & 31) * 2;
    unsigned lo = (unsigned short)f2bf(t[si][d]);
    unsigned hi = (unsigned short)f2bf(t[si + 1][d]);
    *(unsigned*)(vt + ((size_t)(b * D_ + d)) * S_ + st * 64 + si) = lo | (hi << 16);
  }
}

// ==== main fused kernel: per block = 32 q-rows, full S_k, 8 waves ====
// Phase 1: S=QK^T in regs (each wave: 256-col slice, acc[2][16] f32x4)
// Phase 2: exact softmax (shfl + LDS cross-wave reduce)
// Phase 3: attn written fp32 from regs (nontemporal); P -> LDS bf16
// Phase 4: O = P@V via MFMA (4 d-tiles x 2 k-halves across 8 waves)
template <bool WS>
__global__ __launch_bounds__(512, 2)
void attn_kernel(const float* __restrict__ q, const float* __restrict__ k,
                 const float* __restrict__ v, const short* __restrict__ Kb,
                 const short* __restrict__ Vt, float* __restrict__ out,
                 float* __restrict__ attn) {
  __shared__ short P_lds[QBLK][SP];          // 131584 B
  __shared__ float redmax[QBLK][8];
  __shared__ float redsum[QBLK][8];
  __shared__ float Ored[8][16][16];          // 8 KB: PV cross-half reduce

  const int tid  = threadIdx.x;
  const int lane = tid & 63;
  const int wv   = tid >> 6;     // 0..7
  const int lr   = lane & 15;    // row/col-in-tile
  const int lq   = lane >> 4;    // quarter

  const int bid   = blockIdx.x;
  const int b     = bid >> 6;            // S_/QBLK = 64
  const int qbase = (bid & 63) * QBLK;

  // ---------- Phase 1: raw scores ----------
  short8_t aq[2][2];
#pragma unroll
  for (int mt = 0; mt < 2; ++mt) {
    const float* qp = q + ((size_t)(b * S_ + qbase + mt * 16 + lr)) * D_ + lq * 8;
#pragma unroll
    for (int kp = 0; kp < 2; ++kp) {
      f32x4 f0 = *(const f32x4*)(qp + kp * 32);
      f32x4 f1 = *(const f32x4*)(qp + kp * 32 + 4);
      short8_t a;
      a[0] = f2bf(f0[0]); a[1] = f2bf(f0[1]); a[2] = f2bf(f0[2]); a[3] = f2bf(f0[3]);
      a[4] = f2bf(f1[0]); a[5] = f2bf(f1[1]); a[6] = f2bf(f1[2]); a[7] = f2bf(f1[3]);
      aq[mt][kp] = a;
    }
  }

  f32x4 acc[2][16];
#pragma unroll
  for (int mt = 0; mt < 2; ++mt)
#pragma unroll
    for (int ct = 0; ct < 16; ++ct)
      acc[mt][ct] = (f32x4){0.f, 0.f, 0.f, 0.f};

  const int wcol = wv * 256;
#pragma unroll
  for (int ct = 0; ct < 16; ++ct) {
    int n = wcol + ct * 16 + lr;           // key row
    short8_t b0, b1;
    if constexpr (WS) {
      const short* kr = Kb + ((size_t)(b * S_ + n)) * D_ + lq * 8;
      b0 = *(const short8_t*)(kr);
      b1 = *(const short8_t*)(kr + 32);
    } else {
      const float* kr = k + ((size_t)(b * S_ + n)) * D_ + lq * 8;
      f32x4 f0 = *(const f32x4*)(kr);
      f32x4 f1 = *(const f32x4*)(kr + 4);
      f32x4 f2 = *(const f32x4*)(kr + 32);
      f32x4 f3 = *(const f32x4*)(kr + 36);
      b0[0]=f2bf(f0[0]); b0[1]=f2bf(f0[1]); b0[2]=f2bf(f0[2]); b0[3]=f2bf(f0[3]);
      b0[4]=f2bf(f1[0]); b0[5]=f2bf(f1[1]); b0[6]=f2bf(f1[2]); b0[7]=f2bf(f1[3]);
      b1[0]=f2bf(f2[0]); b1[1]=f2bf(f2[1]); b1[2]=f2bf(f2[2]); b1[3]=f2bf(f2[3]);
      b1[4]=f2bf(f3[0]); b1[5]=f2bf(f3[1]); b1[6]=f2bf(f3[2]); b1[7]=f2bf(f3[3]);
    }
    acc[0][ct] = __builtin_amdgcn_mfma_f32_16x16x32_bf16(aq[0][0], b0, acc[0][ct], 0, 0, 0);
    acc[0][ct] = __builtin_amdgcn_mfma_f32_16x16x32_bf16(aq[0][1], b1, acc[0][ct], 0, 0, 0);
    acc[1][ct] = __builtin_amdgcn_mfma_f32_16x16x32_bf16(aq[1][0], b0, acc[1][ct], 0, 0, 0);
    acc[1][ct] = __builtin_amdgcn_mfma_f32_16x16x32_bf16(aq[1][1], b1, acc[1][ct], 0, 0, 0);
  }

  // ---------- Phase 2: softmax ----------
  float mx[2][4];
#pragma unroll
  for (int mt = 0; mt < 2; ++mt)
#pragma unroll
    for (int i = 0; i < 4; ++i) {
      float m = acc[mt][0][i];
#pragma unroll
      for (int ct = 1; ct < 16; ++ct) m = fmaxf(m, acc[mt][ct][i]);
      mx[mt][i] = m;
    }
#pragma unroll
  for (int d = 1; d < 16; d <<= 1)
#pragma unroll
    for (int mt = 0; mt < 2; ++mt)
#pragma unroll
      for (int i = 0; i < 4; ++i)
        mx[mt][i] = fmaxf(mx[mt][i], __shfl_xor(mx[mt][i], d));
  if (lr == 0) {
#pragma unroll
    for (int mt = 0; mt < 2; ++mt)
#pragma unroll
      for (int i = 0; i < 4; ++i)
        redmax[mt * 16 + lq * 4 + i][wv] = mx[mt][i];
  }
  __syncthreads();

  float mfin[2][4], sm[2][4];
#pragma unroll
  for (int mt = 0; mt < 2; ++mt)
#pragma unroll
    for (int i = 0; i < 4; ++i) {
      float m = redmax[mt * 16 + lq * 4 + i][0];
#pragma unroll
      for (int w2 = 1; w2 < 8; ++w2) m = fmaxf(m, redmax[mt * 16 + lq * 4 + i][w2]);
      mfin[mt][i] = m;
      sm[mt][i]   = 0.f;
    }
#pragma unroll
  for (int mt = 0; mt < 2; ++mt)
#pragma unroll
    for (int ct = 0; ct < 16; ++ct)
#pragma unroll
      for (int i = 0; i < 4; ++i) {
        float p = __expf((acc[mt][ct][i] - mfin[mt][i]) * 0.125f);  // /TEMPERATURE
        acc[mt][ct][i] = p;
        sm[mt][i] += p;
      }
#pragma unroll
  for (int d = 1; d < 16; d <<= 1)
#pragma unroll
    for (int mt = 0; mt < 2; ++mt)
#pragma unroll
      for (int i = 0; i < 4; ++i)
        sm[mt][i] += __shfl_xor(sm[mt][i], d);
  if (lr == 0) {
#pragma unroll
    for (int mt = 0; mt < 2; ++mt)
#pragma unroll
      for (int i = 0; i < 4; ++i)
        redsum[mt * 16 + lq * 4 + i][wv] = sm[mt][i];
  }
  __syncthreads();

  float rl[2][4];
#pragma unroll
  for (int mt = 0; mt < 2; ++mt)
#pragma unroll
    for (int i = 0; i < 4; ++i) {
      float s = 0.f;
#pragma unroll
      for (int w2 = 0; w2 < 8; ++w2) s += redsum[mt * 16 + lq * 4 + i][w2];
      rl[mt][i] = 1.f / s;
    }

  // ---------- Phase 3: write attn (fp32, nontemporal) + P_lds (bf16) ----------
  float* ap = attn + (size_t)b * S_ * S_ + (size_t)qbase * S_;
#pragma unroll
  for (int mt = 0; mt < 2; ++mt)
#pragma unroll
    for (int ct = 0; ct < 16; ++ct)
#pragma unroll
      for (int i = 0; i < 4; ++i) {
        int   row = mt * 16 + lq * 4 + i;
        int   col = wcol + ct * 16 + lr;
        float av  = acc[mt][ct][i] * rl[mt][i];
        __builtin_nontemporal_store(av, ap + (size_t)row * S_ + col);
        P_lds[row][col] = f2bf(av);
      }
  __syncthreads();

  // ---------- Phase 4: O = P @ V ----------
  const int cc = wv & 3;       // d-tile
  const int hh = wv >> 2;      // k-half
  const int dbase = cc * 16;
  f32x4 oacc[2];
  oacc[0] = (f32x4){0.f, 0.f, 0.f, 0.f};
  oacc[1] = (f32x4){0.f, 0.f, 0.f, 0.f};
  const short* vrow = WS ? (Vt + ((size_t)(b * D_ + dbase + lr)) * S_) : nullptr;
#pragma unroll 4
  for (int st2 = 0; st2 < 32; ++st2) {
    int kidx = hh * 1024 + st2 * 32 + lq * 8;
    short8_t p0 = *(const short8_t*)&P_lds[lr][kidx];
    short8_t p1 = *(const short8_t*)&P_lds[16 + lr][kidx];
    short8_t vb;
    if constexpr (WS) {
      vb = *(const short8_t*)(vrow + kidx);
    } else {
#pragma unroll
      for (int e = 0; e < 8; ++e)
        vb[e] = f2bf(v[((size_t)(b * S_ + kidx + e)) * D_ + dbase + lr]);
    }
    oacc[0] = __builtin_amdgcn_mfma_f32_16x16x32_bf16(p0, vb, oacc[0], 0, 0, 0);
    oacc[1] = __builtin_amdgcn_mfma_f32_16x16x32_bf16(p1, vb, oacc[1], 0, 0, 0);
  }
  if (hh == 1) {
#pragma unroll
    for (int mt = 0; mt < 2; ++mt)
#pragma unroll
      for (int i = 0; i < 4; ++i)
        Ored[cc * 2 + mt][lq * 4 + i][lr] = oacc[mt][i];
  }
  __syncthreads();
  if (hh == 0) {
#pragma unroll
    for (int mt = 0; mt < 2; ++mt)
#pragma unroll
      for (int i = 0; i < 4; ++i) {
        float o = oacc[mt][i] + Ored[cc * 2 + mt][lq * 4 + i][lr];
        out[((size_t)(b * S_ + qbase + mt * 16 + lq * 4 + i)) * D_ + dbase + lr] = o;
      }
  }
}

extern "C" void kernel_launch(void* const* d_in, const int* in_sizes, int n_in,
                              void* d_out, int out_size, void* d_ws, size_t ws_size,
                              hipStream_t stream) {
  (void)in_sizes; (void)n_in; (void)out_size;
  const float* q = (const float*)d_in[0];
  const float* k = (const float*)d_in[1];
  const float* v = (const float*)d_in[2];
  float* out  = (float*)d_out;
  float* attn = out + (size_t)B_ * S_ * D_;

  const size_t nelem = (size_t)B_ * S_ * D_;        // 4,194,304
  const size_t need  = nelem * 2 * sizeof(short);   // Kb + Vt = 16 MB

  dim3 grid(B_ * (S_ / QBLK));                      // 2048 blocks
  if (d_ws != nullptr && ws_size >= need) {
    short* Kb = (short*)d_ws;
    short* Vt = Kb + nelem;
    convert_bf16_kernel<<<(int)((nelem / 4 + 255) / 256), 256, 0, stream>>>(k, Kb, (int)(nelem / 4));
    transpose_v_kernel<<<B_ * (S_ / 64), 256, 0, stream>>>(v, Vt);
    attn_kernel<true><<<grid, 512, 0, stream>>>(q, k, v, Kb, Vt, out, attn);
  } else {
    attn_kernel<false><<<grid, 512, 0, stream>>>(q, k, v, nullptr, nullptr, out, attn);
  }
}